// Round 1
// baseline (1088.601 us; speedup 1.0000x reference)
//
#include <hip/hip_runtime.h>
#include <math.h>

// ---------------------------------------------------------------------------
// QuantumEnhancedFlow
//   Phase 1 (qkernel): 10-qubit statevector sim, one wave (64 lanes) per
//     sample, 16 complex amps per lane in registers. Writes "enhanced"
//     (q[0:10] ++ x[10:64]) to d_ws  (32768*64 fp32 = 8 MB).
//   Phase 2 (mlpkernel): fused 4-layer MLP + log-prob. 32 rows/block,
//     h-tile in LDS (64 KB, swizzled), W streamed from global (L2-resident).
// ---------------------------------------------------------------------------

#define N_SAMPLES 32768
#define FEAT 64

__device__ __forceinline__ float2 cmul(float2 a, float2 b) {
    return make_float2(a.x*b.x - a.y*b.y, a.x*b.y + a.y*b.x);
}
__device__ __forceinline__ float2 cadd(float2 a, float2 b) {
    return make_float2(a.x + b.x, a.y + b.y);
}
__device__ __forceinline__ float2 shflx2(float2 v, int m) {
    return make_float2(__shfl_xor(v.x, m, 64), __shfl_xor(v.y, m, 64));
}

// ---- encoding gate (real ry-form [[c,-s],[s,c]]) on qubit Q ----
template<int Q>
__device__ __forceinline__ void enc_gate(float2 (&amp)[16], float c, float s, int lane) {
    if constexpr (Q < 4) {
        #pragma unroll
        for (int t = 0; t < 16; ++t) {
            if ((t & (1 << Q)) == 0) {
                const int t1 = t | (1 << Q);
                float2 a = amp[t], b = amp[t1];
                amp[t]  = make_float2(c*a.x - s*b.x, c*a.y - s*b.y);
                amp[t1] = make_float2(s*a.x + c*b.x, s*a.y + c*b.y);
            }
        }
    } else {
        constexpr int xm = 1 << (Q - 4);
        const bool hi = (lane >> (Q - 4)) & 1;
        const float cb = hi ? s : -s;     // lo: c*a - s*b ; hi: c*a + s*b
        #pragma unroll
        for (int t = 0; t < 16; ++t) {
            float2 b = shflx2(amp[t], xm);
            float2 a = amp[t];
            amp[t] = make_float2(c*a.x + cb*b.x, c*a.y + cb*b.y);
        }
    }
}

// ---- combined Rz*Ry*Rx complex gate on qubit Q ----
template<int Q>
__device__ __forceinline__ void rot_gate(float2 (&amp)[16],
                                         float2 g00, float2 g01, float2 g10, float2 g11,
                                         int lane) {
    if constexpr (Q < 4) {
        #pragma unroll
        for (int t = 0; t < 16; ++t) {
            if ((t & (1 << Q)) == 0) {
                const int t1 = t | (1 << Q);
                float2 a = amp[t], b = amp[t1];
                amp[t]  = cadd(cmul(g00, a), cmul(g01, b));
                amp[t1] = cadd(cmul(g10, a), cmul(g11, b));
            }
        }
    } else {
        constexpr int xm = 1 << (Q - 4);
        const bool hi = (lane >> (Q - 4)) & 1;
        float2 ga = hi ? g11 : g00;
        float2 gb = hi ? g10 : g01;
        #pragma unroll
        for (int t = 0; t < 16; ++t) {
            float2 b = shflx2(amp[t], xm);
            amp[t] = cadd(cmul(ga, amp[t]), cmul(gb, b));
        }
    }
}

// ---- CX permutations: new[j] = old[j ^ (bit_C(j) << T)] ----
template<int C, int T>   // both bits local (C<4, T<4)
__device__ __forceinline__ void cx_local(float2 (&amp)[16]) {
    #pragma unroll
    for (int t = 0; t < 16; ++t) {
        if (((t >> C) & 1) && !((t >> T) & 1)) {
            const int t1 = t | (1 << T);
            float2 tmp = amp[t]; amp[t] = amp[t1]; amp[t1] = tmp;
        }
    }
}
// control local bit 3, target lane bit 0
__device__ __forceinline__ void cx_3_4(float2 (&amp)[16]) {
    #pragma unroll
    for (int t = 0; t < 16; ++t)
        if ((t >> 3) & 1) amp[t] = shflx2(amp[t], 1);
}
template<int CL, int TL>  // both lane bits
__device__ __forceinline__ void cx_lane(float2 (&amp)[16], int lane) {
    const bool ctrl = (lane >> CL) & 1;
    #pragma unroll
    for (int t = 0; t < 16; ++t) {
        float2 v = shflx2(amp[t], 1 << TL);
        if (ctrl) amp[t] = v;
    }
}
// control lane bit 5, target local bit 0
__device__ __forceinline__ void cx_9_0(float2 (&amp)[16], int lane) {
    const bool ctrl = (lane >> 5) & 1;
    #pragma unroll
    for (int t = 0; t < 16; t += 2) {
        float2 a = amp[t], b = amp[t + 1];
        amp[t]     = ctrl ? b : a;
        amp[t + 1] = ctrl ? a : b;
    }
}

__global__ __launch_bounds__(256)
void qkernel(const float* __restrict__ x, const float* __restrict__ theta,
             float* __restrict__ enh) {
    __shared__ float2 gbuf[20][4];   // combined Rz*Ry*Rx per (layer,qubit)
    const int tid = threadIdx.x;
    if (tid < 20) {
        const int base = tid * 3;
        float s1, c1, s2, c2, sz, cz;
        sincosf(0.5f * theta[base + 0], &s1, &c1);
        sincosf(0.5f * theta[base + 1], &s2, &c2);
        sincosf(0.5f * theta[base + 2], &sz, &cz);
        // M = Ry*Rx
        float2 m00 = make_float2( c2*c1,  s2*s1);
        float2 m01 = make_float2(-s2*c1, -c2*s1);
        float2 m10 = make_float2( s2*c1, -c2*s1);
        float2 m11 = make_float2( c2*c1, -s2*s1);
        float2 e0 = make_float2(cz, -sz), e1 = make_float2(cz, sz);
        gbuf[tid][0] = cmul(e0, m00);
        gbuf[tid][1] = cmul(e0, m01);
        gbuf[tid][2] = cmul(e1, m10);
        gbuf[tid][3] = cmul(e1, m11);
    }
    __syncthreads();

    const int lane = tid & 63;
    const int s = blockIdx.x * 4 + (tid >> 6);
    const float xr = x[s * FEAT + lane];

    // encoding angle: th/2 = atan(x) -> cos = 1/sqrt(1+x^2), sin = x * that
    const float inv = 1.0f / sqrtf(fmaf(xr, xr, 1.0f));
    const float cq = inv, sq = xr * inv;

    float2 amp[16];
    #pragma unroll
    for (int t = 0; t < 16; ++t) amp[t] = make_float2(0.f, 0.f);
    amp[0].x = (lane == 0) ? 1.0f : 0.0f;

    // ---- encoding rotations ----
    #define ENC(Q) { float c = __shfl(cq, Q, 64); float s_ = __shfl(sq, Q, 64); \
                     enc_gate<Q>(amp, c, s_, lane); }
    ENC(0) ENC(1) ENC(2) ENC(3) ENC(4) ENC(5) ENC(6) ENC(7) ENC(8) ENC(9)
    #undef ENC

    // ---- 2 variational layers ----
    #pragma unroll
    for (int l = 0; l < 2; ++l) {
        const float2* gl = &gbuf[l * 10][0];
        #define ROT(Q) rot_gate<Q>(amp, gl[Q*4+0], gl[Q*4+1], gl[Q*4+2], gl[Q*4+3], lane);
        ROT(0) ROT(1) ROT(2) ROT(3) ROT(4) ROT(5) ROT(6) ROT(7) ROT(8) ROT(9)
        #undef ROT
        cx_local<0,1>(amp); cx_local<1,2>(amp); cx_local<2,3>(amp);
        cx_3_4(amp);
        cx_lane<0,1>(amp, lane); cx_lane<1,2>(amp, lane); cx_lane<2,3>(amp, lane);
        cx_lane<3,4>(amp, lane); cx_lane<4,5>(amp, lane);
        cx_9_0(amp, lane);
    }

    // ---- expectations <Z_i> ----
    float p[16];
    #pragma unroll
    for (int t = 0; t < 16; ++t) p[t] = amp[t].x*amp[t].x + amp[t].y*amp[t].y;
    float o[10];
    #pragma unroll
    for (int i = 0; i < 4; ++i) {
        float acc = 0.f;
        #pragma unroll
        for (int t = 0; t < 16; ++t) acc += ((t >> i) & 1) ? -p[t] : p[t];
        o[i] = acc;
    }
    float ptot = 0.f;
    #pragma unroll
    for (int t = 0; t < 16; ++t) ptot += p[t];
    #pragma unroll
    for (int i = 4; i < 10; ++i) o[i] = ((lane >> (i - 4)) & 1) ? -ptot : ptot;
    #pragma unroll
    for (int i = 0; i < 10; ++i) {
        #pragma unroll
        for (int b = 1; b < 64; b <<= 1) o[i] += __shfl_xor(o[i], b, 64);
    }
    float outv = xr;            // features 10..63 pass through
    #pragma unroll
    for (int i = 0; i < 10; ++i) if (lane == i) outv = o[i];
    enh[s * FEAT + lane] = outv;
}

// ---------------------------------------------------------------------------
// MLP: h LDS tile is 32 rows x 512 cols fp32 (64 KB) with a per-row rotation
// swizzle so the 4 simultaneous row-fragment ds_read_b128 hit distinct banks.
// ---------------------------------------------------------------------------
__device__ __forceinline__ int hidx(int row, int col) {
    return row * 512 + ((col + ((row & 7) << 2)) & 511);
}

template<int K, int N, bool ACT>
__device__ __forceinline__ void mlp_layer(float* hls, const float* __restrict__ W,
                                          const float* __restrict__ bias,
                                          int lane, int w) {
    constexpr int C = N / 64;               // cols per lane (8 or 2)
    const int lr = lane & 3, lc = lane >> 2;
    const int colbase = w * (N / 4);        // wave owns N/4 contiguous cols
    float acc[8][C];
    #pragma unroll
    for (int r = 0; r < 8; ++r)
        #pragma unroll
        for (int c = 0; c < C; ++c) acc[r][c] = 0.f;

    #pragma unroll 2
    for (int k0 = 0; k0 < K; k0 += 4) {
        float4 wv[C];
        #pragma unroll
        for (int c = 0; c < C; ++c)
            wv[c] = *(const float4*)&W[(colbase + lc + 16*c) * K + k0];
        float4 hv[8];
        #pragma unroll
        for (int r = 0; r < 8; ++r)
            hv[r] = *(const float4*)&hls[hidx(lr + 4*r, k0)];
        #pragma unroll
        for (int r = 0; r < 8; ++r)
            #pragma unroll
            for (int c = 0; c < C; ++c) {
                acc[r][c] = fmaf(hv[r].x, wv[c].x, acc[r][c]);
                acc[r][c] = fmaf(hv[r].y, wv[c].y, acc[r][c]);
                acc[r][c] = fmaf(hv[r].z, wv[c].z, acc[r][c]);
                acc[r][c] = fmaf(hv[r].w, wv[c].w, acc[r][c]);
            }
    }
    float bv[C];
    #pragma unroll
    for (int c = 0; c < C; ++c) bv[c] = bias[colbase + lc + 16*c];
    __syncthreads();            // all reads of hls done
    #pragma unroll
    for (int r = 0; r < 8; ++r)
        #pragma unroll
        for (int c = 0; c < C; ++c) {
            float v = acc[r][c] + bv[c];
            if (ACT) v = tanhf(v);
            hls[hidx(lr + 4*r, colbase + lc + 16*c)] = v;
        }
    __syncthreads();
}

__global__ __launch_bounds__(256)
void mlpkernel(const float* __restrict__ enh,
               const float* __restrict__ W_in, const float* __restrict__ b_in,
               const float* __restrict__ W_h,  const float* __restrict__ b_h,
               const float* __restrict__ W_out,const float* __restrict__ b_out,
               float* __restrict__ out) {
    __shared__ float hls[32 * 512];
    const int tid = threadIdx.x;
    const int lane = tid & 63, w = tid >> 6;
    const int row0 = blockIdx.x * 32;

    // stage enhanced[32][64] into hls
    {
        const int i0 = tid * 8;
        const int r = i0 >> 6, c = i0 & 63;
        const float4* src = (const float4*)&enh[(row0 + r) * FEAT + c];
        float4 a = src[0], b = src[1];
        *(float4*)&hls[hidx(r, c)]     = a;
        *(float4*)&hls[hidx(r, c + 4)] = b;
    }
    __syncthreads();

    mlp_layer< 64, 512, true >(hls, W_in,             b_in,      lane, w);
    mlp_layer<512, 512, true >(hls, W_h,              b_h,       lane, w);
    mlp_layer<512, 512, true >(hls, W_h + 512*512,    b_h + 512, lane, w);
    mlp_layer<512, 128, false>(hls, W_out,            b_out,     lane, w);

    // ---- log-prob epilogue: out[r][0:64]=shift, out[r][64:128]=log_scale ----
    const float HALF_LOG2PI = 0.9189385332046727f;
    #pragma unroll
    for (int rr = 0; rr < 8; ++rr) {
        const int row = w * 8 + rr;
        const float shift = hls[hidx(row, lane)];
        const float ls    = hls[hidx(row, 64 + lane)];
        const float e     = enh[(row0 + row) * FEAT + lane];
        const float z = (e - shift) * expf(-ls);
        float term = fmaf(-0.5f * z, z, -HALF_LOG2PI) - ls;
        #pragma unroll
        for (int b = 1; b < 64; b <<= 1) term += __shfl_xor(term, b, 64);
        if (lane == 0) out[row0 + row] = term;
    }
}

extern "C" void kernel_launch(void* const* d_in, const int* in_sizes, int n_in,
                              void* d_out, int out_size, void* d_ws, size_t ws_size,
                              hipStream_t stream) {
    const float* x     = (const float*)d_in[0];
    const float* theta = (const float*)d_in[1];
    const float* W_in  = (const float*)d_in[2];
    const float* b_in  = (const float*)d_in[3];
    const float* W_h   = (const float*)d_in[4];
    const float* b_h   = (const float*)d_in[5];
    const float* W_out = (const float*)d_in[6];
    const float* b_out = (const float*)d_in[7];
    float* out = (float*)d_out;
    float* enh = (float*)d_ws;   // 32768*64 fp32 = 8 MB scratch

    qkernel<<<dim3(N_SAMPLES / 4), dim3(256), 0, stream>>>(x, theta, enh);
    mlpkernel<<<dim3(N_SAMPLES / 32), dim3(256), 0, stream>>>(
        enh, W_in, b_in, W_h, b_h, W_out, b_out, out);
}

// Round 2
// 832.947 us; speedup vs baseline: 1.3069x; 1.3069x over previous
//
#include <hip/hip_runtime.h>
#include <hip/hip_bf16.h>
#include <math.h>

// ---------------------------------------------------------------------------
// QuantumEnhancedFlow — round 2
//   qkernel : unchanged 10-qubit statevector sim (1 wave/sample, regs+shfl)
//   prep    : split fp32 weights into hi/lo bf16 (3-term split-bf16 GEMM)
//   mlpkernel: MFMA-based fused MLP (16x16x32 bf16, 3 MFMA per fp32 product)
//              + log-prob epilogue.
// ws layout: [0,8MB) enh fp32 ; [8MB,10.5MB) W hi/lo bf16
// ---------------------------------------------------------------------------

#define N_SAMPLES 32768
#define FEAT 64

typedef unsigned short u16;
typedef __attribute__((ext_vector_type(8))) short bf16x8_t;
typedef __attribute__((ext_vector_type(4))) float f32x4_t;

__device__ __forceinline__ u16 f2bf(float v) {
    __hip_bfloat16 b = __float2bfloat16(v);
    return __builtin_bit_cast(u16, b);
}
__device__ __forceinline__ float bf2f(u16 u) {
    return __bfloat162float(__builtin_bit_cast(__hip_bfloat16, u));
}

// ===========================================================================
// qkernel (unchanged from round 1)
// ===========================================================================
__device__ __forceinline__ float2 cmul(float2 a, float2 b) {
    return make_float2(a.x*b.x - a.y*b.y, a.x*b.y + a.y*b.x);
}
__device__ __forceinline__ float2 cadd(float2 a, float2 b) {
    return make_float2(a.x + b.x, a.y + b.y);
}
__device__ __forceinline__ float2 shflx2(float2 v, int m) {
    return make_float2(__shfl_xor(v.x, m, 64), __shfl_xor(v.y, m, 64));
}

template<int Q>
__device__ __forceinline__ void enc_gate(float2 (&amp)[16], float c, float s, int lane) {
    if constexpr (Q < 4) {
        #pragma unroll
        for (int t = 0; t < 16; ++t) {
            if ((t & (1 << Q)) == 0) {
                const int t1 = t | (1 << Q);
                float2 a = amp[t], b = amp[t1];
                amp[t]  = make_float2(c*a.x - s*b.x, c*a.y - s*b.y);
                amp[t1] = make_float2(s*a.x + c*b.x, s*a.y + c*b.y);
            }
        }
    } else {
        constexpr int xm = 1 << (Q - 4);
        const bool hi = (lane >> (Q - 4)) & 1;
        const float cb = hi ? s : -s;
        #pragma unroll
        for (int t = 0; t < 16; ++t) {
            float2 b = shflx2(amp[t], xm);
            float2 a = amp[t];
            amp[t] = make_float2(c*a.x + cb*b.x, c*a.y + cb*b.y);
        }
    }
}

template<int Q>
__device__ __forceinline__ void rot_gate(float2 (&amp)[16],
                                         float2 g00, float2 g01, float2 g10, float2 g11,
                                         int lane) {
    if constexpr (Q < 4) {
        #pragma unroll
        for (int t = 0; t < 16; ++t) {
            if ((t & (1 << Q)) == 0) {
                const int t1 = t | (1 << Q);
                float2 a = amp[t], b = amp[t1];
                amp[t]  = cadd(cmul(g00, a), cmul(g01, b));
                amp[t1] = cadd(cmul(g10, a), cmul(g11, b));
            }
        }
    } else {
        constexpr int xm = 1 << (Q - 4);
        const bool hi = (lane >> (Q - 4)) & 1;
        float2 ga = hi ? g11 : g00;
        float2 gb = hi ? g10 : g01;
        #pragma unroll
        for (int t = 0; t < 16; ++t) {
            float2 b = shflx2(amp[t], xm);
            amp[t] = cadd(cmul(ga, amp[t]), cmul(gb, b));
        }
    }
}

template<int C, int T>
__device__ __forceinline__ void cx_local(float2 (&amp)[16]) {
    #pragma unroll
    for (int t = 0; t < 16; ++t) {
        if (((t >> C) & 1) && !((t >> T) & 1)) {
            const int t1 = t | (1 << T);
            float2 tmp = amp[t]; amp[t] = amp[t1]; amp[t1] = tmp;
        }
    }
}
__device__ __forceinline__ void cx_3_4(float2 (&amp)[16]) {
    #pragma unroll
    for (int t = 0; t < 16; ++t)
        if ((t >> 3) & 1) amp[t] = shflx2(amp[t], 1);
}
template<int CL, int TL>
__device__ __forceinline__ void cx_lane(float2 (&amp)[16], int lane) {
    const bool ctrl = (lane >> CL) & 1;
    #pragma unroll
    for (int t = 0; t < 16; ++t) {
        float2 v = shflx2(amp[t], 1 << TL);
        if (ctrl) amp[t] = v;
    }
}
__device__ __forceinline__ void cx_9_0(float2 (&amp)[16], int lane) {
    const bool ctrl = (lane >> 5) & 1;
    #pragma unroll
    for (int t = 0; t < 16; t += 2) {
        float2 a = amp[t], b = amp[t + 1];
        amp[t]     = ctrl ? b : a;
        amp[t + 1] = ctrl ? a : b;
    }
}

__global__ __launch_bounds__(256)
void qkernel(const float* __restrict__ x, const float* __restrict__ theta,
             float* __restrict__ enh) {
    __shared__ float2 gbuf[20][4];
    const int tid = threadIdx.x;
    if (tid < 20) {
        const int base = tid * 3;
        float s1, c1, s2, c2, sz, cz;
        sincosf(0.5f * theta[base + 0], &s1, &c1);
        sincosf(0.5f * theta[base + 1], &s2, &c2);
        sincosf(0.5f * theta[base + 2], &sz, &cz);
        float2 m00 = make_float2( c2*c1,  s2*s1);
        float2 m01 = make_float2(-s2*c1, -c2*s1);
        float2 m10 = make_float2( s2*c1, -c2*s1);
        float2 m11 = make_float2( c2*c1, -s2*s1);
        float2 e0 = make_float2(cz, -sz), e1 = make_float2(cz, sz);
        gbuf[tid][0] = cmul(e0, m00);
        gbuf[tid][1] = cmul(e0, m01);
        gbuf[tid][2] = cmul(e1, m10);
        gbuf[tid][3] = cmul(e1, m11);
    }
    __syncthreads();

    const int lane = tid & 63;
    const int s = blockIdx.x * 4 + (tid >> 6);
    const float xr = x[s * FEAT + lane];

    const float inv = 1.0f / sqrtf(fmaf(xr, xr, 1.0f));
    const float cq = inv, sq = xr * inv;

    float2 amp[16];
    #pragma unroll
    for (int t = 0; t < 16; ++t) amp[t] = make_float2(0.f, 0.f);
    amp[0].x = (lane == 0) ? 1.0f : 0.0f;

    #define ENC(Q) { float c = __shfl(cq, Q, 64); float s_ = __shfl(sq, Q, 64); \
                     enc_gate<Q>(amp, c, s_, lane); }
    ENC(0) ENC(1) ENC(2) ENC(3) ENC(4) ENC(5) ENC(6) ENC(7) ENC(8) ENC(9)
    #undef ENC

    #pragma unroll
    for (int l = 0; l < 2; ++l) {
        const float2* gl = &gbuf[l * 10][0];
        #define ROT(Q) rot_gate<Q>(amp, gl[Q*4+0], gl[Q*4+1], gl[Q*4+2], gl[Q*4+3], lane);
        ROT(0) ROT(1) ROT(2) ROT(3) ROT(4) ROT(5) ROT(6) ROT(7) ROT(8) ROT(9)
        #undef ROT
        cx_local<0,1>(amp); cx_local<1,2>(amp); cx_local<2,3>(amp);
        cx_3_4(amp);
        cx_lane<0,1>(amp, lane); cx_lane<1,2>(amp, lane); cx_lane<2,3>(amp, lane);
        cx_lane<3,4>(amp, lane); cx_lane<4,5>(amp, lane);
        cx_9_0(amp, lane);
    }

    float p[16];
    #pragma unroll
    for (int t = 0; t < 16; ++t) p[t] = amp[t].x*amp[t].x + amp[t].y*amp[t].y;
    float o[10];
    #pragma unroll
    for (int i = 0; i < 4; ++i) {
        float acc = 0.f;
        #pragma unroll
        for (int t = 0; t < 16; ++t) acc += ((t >> i) & 1) ? -p[t] : p[t];
        o[i] = acc;
    }
    float ptot = 0.f;
    #pragma unroll
    for (int t = 0; t < 16; ++t) ptot += p[t];
    #pragma unroll
    for (int i = 4; i < 10; ++i) o[i] = ((lane >> (i - 4)) & 1) ? -ptot : ptot;
    #pragma unroll
    for (int i = 0; i < 10; ++i) {
        #pragma unroll
        for (int b = 1; b < 64; b <<= 1) o[i] += __shfl_xor(o[i], b, 64);
    }
    float outv = xr;
    #pragma unroll
    for (int i = 0; i < 10; ++i) if (lane == i) outv = o[i];
    enh[s * FEAT + lane] = outv;
}

// ===========================================================================
// prep: split fp32 W into hi/lo bf16 arrays (run every call; d_ws is poisoned)
// ===========================================================================
__global__ __launch_bounds__(256)
void prep(const float* __restrict__ W_in, const float* __restrict__ W_h,
          const float* __restrict__ W_out,
          u16* __restrict__ win_hi, u16* __restrict__ win_lo,
          u16* __restrict__ wh_hi,  u16* __restrict__ wh_lo,
          u16* __restrict__ wout_hi,u16* __restrict__ wout_lo) {
    const int i = blockIdx.x * 256 + threadIdx.x;   // grid covers 622592 exactly
    float v; u16 *ph, *pl; int off;
    if (i < 32768)        { v = W_in[i];          ph = win_hi;  pl = win_lo;  off = i; }
    else if (i < 557056)  { off = i - 32768;  v = W_h[off];   ph = wh_hi;   pl = wh_lo;  }
    else                  { off = i - 557056; v = W_out[off]; ph = wout_hi; pl = wout_lo; }
    const u16 hi = f2bf(v);
    const u16 lo = f2bf(v - bf2f(hi));
    ph[off] = hi; pl[off] = lo;
}

// ===========================================================================
// MFMA MLP
//   block = 256 threads (4 waves), 32 rows. LDS: h hi/lo [32][512] bf16 (64KB)
//   XOR swizzle: logical (m,k) stored at m*K + (((k>>3)^(m&7))*8) + (k&7)
//   A-frag: lane reads row m=mt*16+(lane&15), k0=(ks*4+(lane>>4))*8  (b128)
//   B-frag: lane reads W row n=colbase+nt*16+(lane&15), same k window (b128)
//   D: col = lane&15 (n), row = (lane>>4)*4+reg (m)   [m89/m91-verified]
// ===========================================================================

template<int K, int NT>
__device__ __forceinline__ void gemm_frag(
        const u16* __restrict__ Whi, const u16* __restrict__ Wlo,
        const u16* hHi, const u16* hLo, int lane, int colbase,
        f32x4_t (&acc)[2][NT]) {
    #pragma unroll
    for (int mt = 0; mt < 2; ++mt)
        #pragma unroll
        for (int nt = 0; nt < NT; ++nt) acc[mt][nt] = (f32x4_t)0.f;

    const int l15 = lane & 15, l4 = lane >> 4, l7 = lane & 7;
    #pragma unroll 2
    for (int ks = 0; ks < K / 32; ++ks) {
        bf16x8_t aH[2], aL[2];
        #pragma unroll
        for (int mt = 0; mt < 2; ++mt) {
            const int m   = mt * 16 + l15;
            const int blk = (ks * 4 + l4) ^ l7;
            const int off = m * K + blk * 8;
            aH[mt] = *(const bf16x8_t*)&hHi[off];
            aL[mt] = *(const bf16x8_t*)&hLo[off];
        }
        bf16x8_t bH[NT], bL[NT];
        #pragma unroll
        for (int nt = 0; nt < NT; ++nt) {
            const int n    = colbase + nt * 16 + l15;
            const int boff = n * K + ks * 32 + l4 * 8;
            bH[nt] = *(const bf16x8_t*)&Whi[boff];
            bL[nt] = *(const bf16x8_t*)&Wlo[boff];
        }
        #pragma unroll
        for (int nt = 0; nt < NT; ++nt)
            #pragma unroll
            for (int mt = 0; mt < 2; ++mt) {
                acc[mt][nt] = __builtin_amdgcn_mfma_f32_16x16x32_bf16(aH[mt], bH[nt], acc[mt][nt], 0, 0, 0);
                acc[mt][nt] = __builtin_amdgcn_mfma_f32_16x16x32_bf16(aH[mt], bL[nt], acc[mt][nt], 0, 0, 0);
                acc[mt][nt] = __builtin_amdgcn_mfma_f32_16x16x32_bf16(aL[mt], bH[nt], acc[mt][nt], 0, 0, 0);
            }
    }
}

template<int NT>
__device__ __forceinline__ void write_h(
        f32x4_t (&acc)[2][NT], const float* __restrict__ bias,
        u16* hHi, u16* hLo, int lane, int colbase) {
    const int l15 = lane & 15, l4 = lane >> 4;
    #pragma unroll
    for (int nt = 0; nt < NT; ++nt) {
        const int n = colbase + nt * 16 + l15;
        const float b = bias[n];
        #pragma unroll
        for (int mt = 0; mt < 2; ++mt)
            #pragma unroll
            for (int r = 0; r < 4; ++r) {
                const int m = mt * 16 + l4 * 4 + r;
                const float v = tanhf(acc[mt][nt][r] + b);
                const u16 hi = f2bf(v);
                const u16 lo = f2bf(v - bf2f(hi));
                const int blk = (n >> 3) ^ (m & 7);
                const int off = m * 512 + blk * 8 + (n & 7);
                hHi[off] = hi; hLo[off] = lo;
            }
    }
}

__global__ __launch_bounds__(256, 2)
void mlpkernel(const float* __restrict__ enh,
               const u16* __restrict__ win_hi, const u16* __restrict__ win_lo,
               const float* __restrict__ b_in,
               const u16* __restrict__ wh_hi,  const u16* __restrict__ wh_lo,
               const float* __restrict__ b_h,
               const u16* __restrict__ wout_hi,const u16* __restrict__ wout_lo,
               const float* __restrict__ b_out,
               float* __restrict__ out) {
    __shared__ u16 hHi[32 * 512];
    __shared__ u16 hLo[32 * 512];
    const int tid = threadIdx.x;
    const int lane = tid & 63, w = tid >> 6;
    const int row0 = blockIdx.x * 32;

    // ---- stage enhanced[32][64] -> LDS hi/lo (K=64 layout, swizzled) ----
    {
        const int r = tid >> 3, c0 = (tid & 7) * 8;
        const float4 v0 = *(const float4*)&enh[(row0 + r) * FEAT + c0];
        const float4 v1 = *(const float4*)&enh[(row0 + r) * FEAT + c0 + 4];
        const float vv[8] = {v0.x, v0.y, v0.z, v0.w, v1.x, v1.y, v1.z, v1.w};
        bf16x8_t vh, vl;
        #pragma unroll
        for (int j = 0; j < 8; ++j) {
            const u16 hi = f2bf(vv[j]);
            const u16 lo = f2bf(vv[j] - bf2f(hi));
            vh[j] = (short)hi; vl[j] = (short)lo;
        }
        const int off = r * 64 + (((c0 >> 3) ^ (r & 7)) * 8);
        *(bf16x8_t*)&hHi[off] = vh;
        *(bf16x8_t*)&hLo[off] = vl;
    }
    __syncthreads();

    f32x4_t acc[2][8];
    // layer 1: 64 -> 512
    gemm_frag<64, 8>(win_hi, win_lo, hHi, hLo, lane, w * 128, acc);
    __syncthreads();
    write_h<8>(acc, b_in, hHi, hLo, lane, w * 128);
    __syncthreads();
    // layer 2: 512 -> 512
    gemm_frag<512, 8>(wh_hi, wh_lo, hHi, hLo, lane, w * 128, acc);
    __syncthreads();
    write_h<8>(acc, b_h, hHi, hLo, lane, w * 128);
    __syncthreads();
    // layer 3: 512 -> 512
    gemm_frag<512, 8>(wh_hi + 262144, wh_lo + 262144, hHi, hLo, lane, w * 128, acc);
    __syncthreads();
    write_h<8>(acc, b_h + 512, hHi, hLo, lane, w * 128);
    __syncthreads();
    // layer 4: 512 -> 128 (no activation)
    f32x4_t acc2[2][2];
    gemm_frag<512, 2>(wout_hi, wout_lo, hHi, hLo, lane, w * 32, acc2);
    __syncthreads();

    float* f = (float*)hHi;     // reuse LDS: out tile [32][128] fp32 (16KB)
    {
        const int l15 = lane & 15, l4 = lane >> 4;
        #pragma unroll
        for (int nt = 0; nt < 2; ++nt) {
            const int n = w * 32 + nt * 16 + l15;
            const float b = b_out[n];
            #pragma unroll
            for (int mt = 0; mt < 2; ++mt)
                #pragma unroll
                for (int r = 0; r < 4; ++r) {
                    const int m = mt * 16 + l4 * 4 + r;
                    f[m * 128 + n] = acc2[mt][nt][r] + b;
                }
        }
    }
    __syncthreads();

    // ---- log-prob epilogue ----
    const float HALF_LOG2PI = 0.9189385332046727f;
    #pragma unroll
    for (int rr = 0; rr < 8; ++rr) {
        const int row = w * 8 + rr;
        const float shift = f[row * 128 + lane];
        const float ls    = f[row * 128 + 64 + lane];
        const float e     = enh[(row0 + row) * FEAT + lane];
        const float z = (e - shift) * expf(-ls);
        float term = fmaf(-0.5f * z, z, -HALF_LOG2PI) - ls;
        #pragma unroll
        for (int b = 1; b < 64; b <<= 1) term += __shfl_xor(term, b, 64);
        if (lane == 0) out[row0 + row] = term;
    }
}

extern "C" void kernel_launch(void* const* d_in, const int* in_sizes, int n_in,
                              void* d_out, int out_size, void* d_ws, size_t ws_size,
                              hipStream_t stream) {
    const float* x     = (const float*)d_in[0];
    const float* theta = (const float*)d_in[1];
    const float* W_in  = (const float*)d_in[2];
    const float* b_in  = (const float*)d_in[3];
    const float* W_h   = (const float*)d_in[4];
    const float* b_h   = (const float*)d_in[5];
    const float* W_out = (const float*)d_in[6];
    const float* b_out = (const float*)d_in[7];
    float* out = (float*)d_out;

    float* enh = (float*)d_ws;                                    // 8 MB
    u16* wbuf = (u16*)((char*)d_ws + (size_t)N_SAMPLES * FEAT * 4);
    u16* win_hi  = wbuf;                  // 512*64
    u16* win_lo  = win_hi + 32768;
    u16* wh_hi   = win_lo + 32768;        // 2*512*512
    u16* wh_lo   = wh_hi + 524288;
    u16* wout_hi = wh_lo + 524288;        // 128*512
    u16* wout_lo = wout_hi + 65536;

    qkernel<<<dim3(N_SAMPLES / 4), dim3(256), 0, stream>>>(x, theta, enh);
    prep<<<dim3(2432), dim3(256), 0, stream>>>(W_in, W_h, W_out,
        win_hi, win_lo, wh_hi, wh_lo, wout_hi, wout_lo);
    mlpkernel<<<dim3(N_SAMPLES / 32), dim3(256), 0, stream>>>(
        enh, win_hi, win_lo, b_in, wh_hi, wh_lo, b_h, wout_hi, wout_lo, b_out, out);
}